// Round 14
// baseline (233.320 us; speedup 1.0000x reference)
//
#include <hip/hip_runtime.h>
#include <stdint.h>

typedef int   int32x4   __attribute__((ext_vector_type(4)));
typedef int   int32x16  __attribute__((ext_vector_type(16)));
typedef float floatx4   __attribute__((ext_vector_type(4)));

#define B_ROWS 131072
#define DK 512           // K (= D)
#define FN 512           // N (= F)
#define A_SCALE_F ((float)(127.0 / 6.0))

// fused-GEMM geometry: 1024 blocks x 256 threads (4 waves). Block b covers
// col-half (b&1)*256 and rows (b>>1)*256. Two 4-wave blocks co-resident per CU
// (same 8 waves/CU, 256 regs/wave as R13) -> two independent barrier domains:
// one block's barrier stall is filled by the other's MFMA/load issue.
// Pair (2k,2k+1) shares the same x rows and is co-resident -> L3 absorbs the
// second read.
#define GBLK 1024
#define GT   256
#define BMS  32
#define GTILES (B_ROWS / BMS / (GBLK / 2))   // 8

// ---------------- prepass: quantize weights into B-fragment layout -------------
__global__ void wq_quant_kernel(const float* __restrict__ kern,  // [DK][FN]
                                int8_t* __restrict__ wq,         // [FN][DK]
                                float* __restrict__ invcs) {     // [FN]
  __shared__ float smax[256];
  __shared__ float sscale[4];
  const int c = threadIdx.x & 3;         // col within block
  const int g = threadIdx.x >> 2;        // row-group 0..63 (8 rows each)
  const int col = blockIdx.x * 4 + c;

  float m = 0.f;
#pragma unroll
  for (int i = 0; i < 8; ++i) {
    m = fmaxf(m, fabsf(kern[(size_t)(g * 8 + i) * FN + col]));
  }
  smax[threadIdx.x] = m;
  __syncthreads();
  if (threadIdx.x < 4) {
    float mm = smax[threadIdx.x];
#pragma unroll 8
    for (int g2 = 1; g2 < 64; ++g2) mm = fmaxf(mm, smax[g2 * 4 + threadIdx.x]);
    const float wb = fmaxf(mm, 1e-6f);
    const float ws = 127.f / wb;               // f32 divide, matches jnp w_scale
    sscale[threadIdx.x] = ws;
    invcs[blockIdx.x * 4 + threadIdx.x] =
        (float)(1.0 / ((double)A_SCALE_F * (double)ws));
  }
  __syncthreads();
  const float ws = sscale[c];
  uint32_t* wq32 = (uint32_t*)(wq + (size_t)col * DK);
#pragma unroll
  for (int d = 0; d < 2; ++d) {                // 8 rows -> 2 packed words
    uint32_t p = 0;
#pragma unroll
    for (int j = 0; j < 4; ++j) {
      float v = kern[(size_t)(g * 8 + d * 4 + j) * FN + col] * ws;
      v = floorf(v + 0.5f);                    // AQT round: floor(v+0.5)
      v = fminf(fmaxf(v, -127.f), 127.f);
      p |= ((uint32_t)((int)v & 255)) << (8 * j);
    }
    wq32[g * 2 + d] = p;
  }
}

// ---------------- fused GEMM: 4-wave blocks, 2/CU, 1-deep prefetch -------------
// Loads for tile t+1 are issued before tile t's panels (loads oldest in the
// vmem queue -> the quantize's wait never drains the panel stores). Sibling
// block on the CU fills barrier/latency gaps (TLP replaces the 2-deep ILP).
__device__ __forceinline__ uint32_t quant4(floatx4 v) {
  uint32_t p = 0;
#pragma unroll
  for (int j = 0; j < 4; ++j) {
    float q = floorf(v[j] * A_SCALE_F + 0.5f);   // AQT round: floor(v+0.5)
    q = fminf(fmaxf(q, -127.f), 127.f);
    p |= ((uint32_t)((int)q & 255)) << (8 * j);
  }
  return p;
}

__global__ __launch_bounds__(GT, 2)
void aqt_gemm_fused(const float* __restrict__ x,     // [B_ROWS][DK]
                    const int8_t* __restrict__ wq,   // [FN][DK]
                    const float* __restrict__ invcs, // [FN]
                    const float* __restrict__ bias,  // [FN]
                    float* __restrict__ out) {       // [B_ROWS][FN]
  __shared__ __align__(16) uint8_t xq[2][BMS * DK];  // 2 x 16 KB

  const int tid  = threadIdx.x;
  const int lane = tid & 63;
  const int wv   = tid >> 6;       // 0..3 -> 64-col strip within the half
  const int l31  = lane & 31;
  const int l5   = lane >> 5;

  const int c4 = tid & 127;        // float4 col within a row
  const int rg = tid >> 7;         // 0..1 -> rows rg, rg+2, ..., rg+30

  // ---- B fragments into registers, once (256 KB, L2-hot): 2 panels ----
  const int half = blockIdx.x & 1;
  const int col0 = half * 256 + wv * 64 + l31;
  const int col1 = col0 + 32;
  int32x4 Bf0[16], Bf1[16];
#pragma unroll
  for (int ks = 0; ks < 16; ++ks) {
    Bf0[ks] = *(const int32x4*)(wq + (size_t)col0 * DK + ks * 32 + l5 * 16);
    Bf1[ks] = *(const int32x4*)(wq + (size_t)col1 * DK + ks * 32 + l5 * 16);
  }
  const float inv0 = invcs[col0], bv0 = bias[col0];
  const float inv1 = invcs[col1], bv1 = bias[col1];

  const size_t row0 = (size_t)(blockIdx.x >> 1) * (GTILES * BMS);

  // issue the 16 f32 tile loads for tile starting at row rt
#define LOADV(vdst, rt)                                                       \
  {                                                                           \
    const float* xg_ = x + (size_t)(rt) * DK;                                 \
    _Pragma("unroll")                                                         \
    for (int i_ = 0; i_ < 16; ++i_)                                           \
      vdst[i_] = *(const floatx4*)(xg_ + (size_t)(i_ * 2 + rg) * DK + c4 * 4);\
  }

  // quantize 16 granules into LDS buffer (XOR-swizzled)
#define QWRITE(vsrc, bufp)                                                    \
  {                                                                           \
    _Pragma("unroll")                                                         \
    for (int i_ = 0; i_ < 16; ++i_) {                                         \
      const int r_ = i_ * 2 + rg;                                             \
      *(uint32_t*)(&(bufp)[r_ * DK + ((c4 * 4) ^ ((r_ & 31) << 4))]) =        \
          quant4(vsrc[i_]);                                                   \
    }                                                                         \
  }

  // one 32-col panel: K-loop + epilogue NT stores (acc lives only inside)
#define PANEL(Bf, colv, invv, bvv, bufp, rt)                                  \
  {                                                                           \
    int32x16 acc = (int32x16)(0);                                             \
    const uint8_t* aRow_ = (bufp) + l31 * DK;                                 \
    _Pragma("unroll")                                                         \
    for (int ks_ = 0; ks_ < 16; ++ks_) {                                      \
      int32x4 a_ = *(const int32x4*)(aRow_ + ((ks_ * 32 + l5 * 16) ^ (l31 << 4))); \
      acc = __builtin_amdgcn_mfma_i32_32x32x32_i8(a_, Bf[ks_], acc, 0, 0, 0); \
    }                                                                         \
    _Pragma("unroll")                                                         \
    for (int r_ = 0; r_ < 16; ++r_) {                                         \
      const int rowl_ = (r_ & 3) + 8 * (r_ >> 2) + 4 * l5;                    \
      __builtin_nontemporal_store((float)acc[r_] * (invv) + (bvv),            \
                                  &out[((rt) + rowl_) * FN + (colv)]);        \
    }                                                                         \
  }

  floatx4 vA[16];

  // ---- prologue: tile 0 staged (startup stall, once) ----
  LOADV(vA, row0);
  QWRITE(vA, (&xq[0][0]));
  asm volatile("s_waitcnt lgkmcnt(0)" ::: "memory");
  __builtin_amdgcn_s_barrier();

#pragma unroll 1
  for (int t = 0; t < GTILES; ++t) {
    const size_t rowT = row0 + (size_t)t * BMS;
    const uint8_t* bufC = &xq[t & 1][0];
    uint8_t* bufN = &xq[(t & 1) ^ 1][0];
    const bool pf = (t + 1 < GTILES);

    // loads for t+1 issued FIRST (oldest in vmem queue; panels' stores newer)
    if (pf) LOADV(vA, rowT + BMS);
    PANEL(Bf0, col0, inv0, bv0, bufC, rowT);
    PANEL(Bf1, col1, inv1, bv1, bufC, rowT);
    if (pf) QWRITE(vA, bufN);        // waits only on the 16 loads, not stores

    asm volatile("s_waitcnt lgkmcnt(0)" ::: "memory");
    __builtin_amdgcn_s_barrier();
  }

#undef LOADV
#undef QWRITE
#undef PANEL
}

extern "C" void kernel_launch(void* const* d_in, const int* in_sizes, int n_in,
                              void* d_out, int out_size, void* d_ws, size_t ws_size,
                              hipStream_t stream) {
  const float* x    = (const float*)d_in[0];
  const float* kern = (const float*)d_in[1];
  const float* bias = (const float*)d_in[2];
  // d_in[3] = padding_mask: fixed act bounds + eval mode -> not in the math.

  int8_t* wq    = (int8_t*)d_ws;                            // 256 KB
  float*  invcs = (float*)((char*)d_ws + (size_t)FN * DK);  // 2 KB

  wq_quant_kernel<<<128, 256, 0, stream>>>(kern, wq, invcs);
  aqt_gemm_fused<<<GBLK, GT, 0, stream>>>(x, wq, invcs, bias, (float*)d_out);
}